// Round 10
// baseline (62191.809 us; speedup 1.0000x reference)
//
#include <hip/hip_runtime.h>
#include <hip/hip_bf16.h>

#define Bdim 128
#define Tdim 256
#define DIN 512
#define Hdim 1024
#define Sdim 128
#define DHdim 1024
#define KG 1152   // S + H (gates GEMM K)
#define KP 1536   // DIN + H (heads GEMM K)
#define GBLK 32   // gates blocks: 8 row-groups x 4 macro-slices (16r x 1024 gate-cols)
#define HBLK 16   // heads blocks: 8 row-groups x 2 (4 s-slices each)
#define NBLK 48
#define LDP 1160  // gates LDS A-panel row stride (1152 + 8 pad)

using short8  = __attribute__((ext_vector_type(8))) short;   // 8 bf16 (4 VGPRs)
using floatx4 = __attribute__((ext_vector_type(4))) float;   // MFMA accum
typedef unsigned long long ull;

#define MFMA(a, b, c) __builtin_amdgcn_mfma_f32_16x16x32_bf16((a), (b), (c), 0, 0, 0)

// ---- workspace layout (bytes). Scan-phase staging (xbf/Wg/Wmv) unions with
// Hbuf (decoder intermediate), which is written only after the scan finishes.
#define XBF_OFF   0ull            // 128*256*512 bf16 = 33,554,432
#define WG_OFF    33554432ull     // 4096*1152 bf16 = 9,437,184
#define WMV_OFF   42991616ull     // 256*1536 bf16 = 786,432
#define HB_OFF    0ull            // 32768*1024 bf16 = 67,108,864 (unions scan staging)
#define WD1_OFF   67108864ull     // 1024*128 bf16 = 262,144
#define WD2_OFF   67371008ull     // 512*1024 bf16 = 1,048,576
#define AB_OFF    68419584ull     // 2 x 128*1152 bf16 (ping-pong [z|h]) = 589,824
#define AB_SZ     294912ull
#define ZALL_OFF  69009408ull     // 32768*128 bf16 = 8,388,608
#define KL_OFF    77398016ull     // 1 f32
#define FLG_OFF   77398144ull     // u32 monotonic per-producer seqno flags

__device__ __forceinline__ float sigf(float v) { return 1.0f / (1.0f + __expf(-v)); }
__device__ __forceinline__ float tanhfast(float v) { return 1.0f - 2.0f / (__expf(2.0f * v) + 1.0f); }

// 16B agent-coherent load: ONE coherent transaction.
// Protocol (vmcnt-accounting safety, round-1 lesson): asm loads only outstanding
// inside a staging burst, drained by VMWAIT0 before ANY compiler memory op.
__device__ __forceinline__ short8 cload16(const __hip_bfloat16* p) {
  short8 r;
  asm volatile("global_load_dwordx4 %0, %1, off sc0 sc1" : "=&v"(r) : "v"(p));
  return r;
}
#define VMWAIT0()                                              \
  do {                                                         \
    asm volatile("s_waitcnt vmcnt(0)" ::: "memory");           \
    __builtin_amdgcn_sched_barrier(0);                         \
  } while (0)
#define SB0() __builtin_amdgcn_sched_barrier(0)

__device__ __forceinline__ void astore8(__hip_bfloat16* p, ull v) {
  __hip_atomic_store((ull*)(void*)p, v, __ATOMIC_RELAXED, __HIP_MEMORY_SCOPE_AGENT);
}

// Wave0-only polling + s_sleep(8) backoff (round-3 proven); callers release the
// other waves with __syncthreads().
__device__ __forceinline__ void waitflags(unsigned* flags, int base, int mask,
                                          unsigned target, int lane) {
  unsigned* p = flags + base + (lane & mask);
  while (!__all((int)(__hip_atomic_load(p, __ATOMIC_RELAXED, __HIP_MEMORY_SCOPE_AGENT) >= target))) {
    __builtin_amdgcn_s_sleep(8);
  }
}

// ---------------- prep: fp32->bf16 conversions, weight packing, state zeroing
__global__ __launch_bounds__(256) void prep_kernel(
    const float* __restrict__ x, const float* __restrict__ W_ih,
    const float* __restrict__ W_hh, const float* __restrict__ Wm,
    const float* __restrict__ Wv, const float* __restrict__ Wd1,
    const float* __restrict__ Wd2, char* __restrict__ ws) {
  long long i = (long long)blockIdx.x * 256 + threadIdx.x;
  if (i < 16777216LL) {  // x -> xbf  [B][T][DIN]
    ((__hip_bfloat16*)(ws + XBF_OFF))[i] = __float2bfloat16(x[i]);
    return;
  }
  i -= 16777216LL;
  if (i < 4718592LL) {  // Wg[4096][1152] = [W_ih | W_hh]
    int j = (int)(i / KG), k = (int)(i % KG);
    float v = (k < Sdim) ? W_ih[j * Sdim + k] : W_hh[(long long)j * Hdim + (k - Sdim)];
    ((__hip_bfloat16*)(ws + WG_OFF))[i] = __float2bfloat16(v);
    return;
  }
  i -= 4718592LL;
  if (i < 393216LL) {  // Wmv[256][1536] = [Wm ; Wv]
    int r = (int)(i / KP), k = (int)(i % KP);
    float v = (r < Sdim) ? Wm[r * KP + k] : Wv[(r - Sdim) * KP + k];
    ((__hip_bfloat16*)(ws + WMV_OFF))[i] = __float2bfloat16(v);
    return;
  }
  i -= 393216LL;
  if (i < 131072LL) { ((__hip_bfloat16*)(ws + WD1_OFF))[i] = __float2bfloat16(Wd1[i]); return; }
  i -= 131072LL;
  if (i < 524288LL) { ((__hip_bfloat16*)(ws + WD2_OFF))[i] = __float2bfloat16(Wd2[i]); return; }
  i -= 524288LL;
  if (i < 147456LL) { ((__hip_bfloat16*)(ws + AB_OFF))[i] = __float2bfloat16(0.0f); return; }  // [z0|h0]=0
  i -= 147456LL;
  if (i == 0) { *((float*)(ws + KL_OFF)) = 0.0f; return; }
  i -= 1;
  if (i < 192LL) { ((unsigned*)(ws + FLG_OFF))[i] = 0u; return; }
}

// ---------------- persistent scan: whole T=256 recurrence in ONE kernel.
// Round-10: temporal slice reuse on the r9 structure.
//  Gates block b<32 (mgrp=b>>2, nsb=b&3): 16-row LDS A-panel staged once/step,
//   then 4 col-slices (4 gates x 64 hcols each) computed sequentially with the
//   EXACT r3 per-wave inner shape (acc[4], 4 weight streams). A-traffic 4.7->1.2 MB/step.
//  Heads block 32+hb, hb<16 (mb=hb>>1, sbb=(hb&1)*4): areg[12] (x+h) loaded once,
//   reused for 4 s-slices. Heads h-traffic 2->0.5 MB/step.
// Flags: [0..31] gates (cohort mgrp*4 mask 3), [32..47] heads (pair per mb).
__global__ __launch_bounds__(256, 1) void scan_kernel(
    char* __restrict__ ws, const float* __restrict__ noise,
    const float* __restrict__ b_ih, const float* __restrict__ b_hh,
    const float* __restrict__ bm, const float* __restrict__ bv) {
  const __hip_bfloat16* WG = (const __hip_bfloat16*)(ws + WG_OFF);
  const __hip_bfloat16* WMV = (const __hip_bfloat16*)(ws + WMV_OFF);
  const __hip_bfloat16* xbf = (const __hip_bfloat16*)(ws + XBF_OFF);
  __hip_bfloat16* zall = (__hip_bfloat16*)(ws + ZALL_OFF);
  float* klacc = (float*)(ws + KL_OFF);
  unsigned* flags = (unsigned*)(ws + FLG_OFF);

  // gates: bf16 A-panel [16][LDP] = 37120 B. heads: f32 reduce smem (8 KB). union.
  __shared__ __align__(16) char ldsraw[16 * LDP * 2];
  __hip_bfloat16* lds = (__hip_bfloat16*)ldsraw;
  float* smem = (float*)ldsraw;

  const int tid = threadIdx.x;
  const int lane = tid & 63;
  const int w = tid >> 6;
  const int row16 = lane & 15;
  const int quad = lane >> 4;
  const int bid = blockIdx.x;
  const bool is_gates = (bid < GBLK);

  // ---- gates-role setup
  const __hip_bfloat16* wb[4];   // weight row base per gate (slice 0)
  float biasv[4][4];             // [slice][gate]
  float creg[4][4];              // [slice][r]
  int mgrp = 0, nsb = 0, rowbase = 0;
  // ---- heads-role setup
  const __hip_bfloat16* hd_bpm = nullptr;  // slice 0 bases
  const __hip_bfloat16* hd_bpv = nullptr;
  int hd_mb = 0, hd_sbb = 0, hd_nx = 0, hd_kbase = 0;
  float hbm4[4], hbv4[4];
  float klw = 0.f;  // heads w0: KL accumulated over all t

  if (is_gates) {
    mgrp = bid >> 2;
    nsb = bid & 3;
    rowbase = mgrp * 16;
    #pragma unroll
    for (int j = 0; j < 4; j++)
      wb[j] = WG + (size_t)(j * Hdim + nsb * 256 + w * 16 + row16) * KG;
    #pragma unroll
    for (int s = 0; s < 4; s++)
      #pragma unroll
      for (int j = 0; j < 4; j++) {
        int idx = j * Hdim + nsb * 256 + s * 64 + w * 16 + row16;
        biasv[s][j] = b_ih[idx] + b_hh[idx];
        creg[s][j] = 0.0f;  // (reuse [s][j] as [s][r]: both 4x4, init all)
      }
  } else {
    int hb = bid - GBLK;
    hd_mb = hb >> 1;
    hd_sbb = (hb & 1) * 4;
    int s0 = hd_sbb * 16 + row16;
    hd_bpm = WMV + (size_t)s0 * KP;
    hd_bpv = WMV + (size_t)(128 + s0) * KP;
    #pragma unroll
    for (int ss = 0; ss < 4; ss++) {
      hbm4[ss] = bm[(hd_sbb + ss) * 16 + row16];
      hbv4[ss] = bv[(hd_sbb + ss) * 16 + row16];
    }
    hd_kbase = w * 384;
    hd_nx = (hd_kbase < DIN) ? ((DIN - hd_kbase) >> 5) : 0;  // 12,4,0,0
    if (hd_nx > 12) hd_nx = 12;
  }

  for (int t = 0; t < Tdim; t++) {
    const int par = t & 1;
    const __hip_bfloat16* Ab = (const __hip_bfloat16*)(ws + AB_OFF + (ull)par * AB_SZ);
    __hip_bfloat16* AbW = (__hip_bfloat16*)(ws + AB_OFF + (ull)(par ^ 1) * AB_SZ);

    if (is_gates) {
      // --- h-wait (own 4-block cohort: WAR + h(t-1) ready)
      if (w == 0) waitflags(flags, mgrp * 4, 3, (unsigned)t, lane);
      __syncthreads();  // release: data ordered after wave0's flag observation
      // --- stage h-panel into LDS: 16 rows x 1024 cols = 2048 16B-segs, 8/thread
      {
        short8 sreg[8];
        #pragma unroll
        for (int i = 0; i < 8; i++) {
          int s = tid + i * 256;
          sreg[i] = cload16(Ab + (size_t)(rowbase + (s >> 7)) * KG + Sdim + (s & 127) * 8);
        }
        VMWAIT0();  // drain asm loads before compiler ds_writes
        #pragma unroll
        for (int i = 0; i < 8; i++) {
          int s = tid + i * 256;
          *(short8*)&lds[(s >> 7) * LDP + Sdim + (s & 127) * 8] = sreg[i];
        }
      }
      __syncthreads();  // panel visible to all waves

      floatx4 acc[4];
      // ---- slice 0: h-MFMA first (overlaps heads' phase), then z-wait
      #pragma unroll
      for (int j = 0; j < 4; j++)
        acc[j] = (floatx4){biasv[0][j], biasv[0][j], biasv[0][j], biasv[0][j]};
      #pragma unroll
      for (int c = 0; c < 8; c++) {
        #pragma unroll
        for (int i = 0; i < 4; i++) {
          const int k0 = Sdim + (c * 4 + i) * 32 + quad * 8;
          short8 a = *(const short8*)&lds[row16 * LDP + k0];
          #pragma unroll
          for (int j = 0; j < 4; j++)
            acc[j] = MFMA(a, *(const short8*)(wb[j] + k0), acc[j]);
        }
        SB0();
      }
      // --- z-wait (heads pair for my rows, t-1) + stage z: 256 segs, 1/thread
      if (w == 0) waitflags(flags, GBLK + mgrp * 2, 1, (unsigned)t, lane);
      __syncthreads();
      {
        short8 zs = cload16(Ab + (size_t)(rowbase + (tid >> 4)) * KG + (tid & 15) * 8);
        VMWAIT0();
        *(short8*)&lds[(tid >> 4) * LDP + (tid & 15) * 8] = zs;
      }
      __syncthreads();
      // ---- finish slice 0: z-MFMA + LSTM + store
      #pragma unroll
      for (int kt = 0; kt < 4; kt++) {
        const int k0 = kt * 32 + quad * 8;
        short8 a = *(const short8*)&lds[row16 * LDP + k0];
        #pragma unroll
        for (int j = 0; j < 4; j++)
          acc[j] = MFMA(a, *(const short8*)(wb[j] + k0), acc[j]);
      }
      SB0();
      #pragma unroll
      for (int r = 0; r < 4; r++) {
        float cn = sigf(acc[1][r]) * creg[0][r] + sigf(acc[0][r]) * tanhfast(acc[2][r]);
        creg[0][r] = cn;
        float hn = sigf(acc[3][r]) * tanhfast(cn);
        __hip_bfloat16 hbf = __float2bfloat16(hn);
        unsigned hu = (unsigned)reinterpret_cast<unsigned short&>(hbf);
        unsigned up = hu | (__shfl_xor(hu, 1, 64) << 16);
        unsigned uq = __shfl_xor(up, 2, 64);
        if ((row16 & 3) == 0) {
          int grow = rowbase + quad * 4 + r;
          int hc = nsb * 256 + 0 * 64 + w * 16 + row16;
          astore8(AbW + (size_t)grow * KG + Sdim + hc, (ull)up | ((ull)uq << 32));
        }
      }
      // ---- slices 1..3: full K from LDS (h + z), LSTM, store
      #pragma unroll
      for (int s = 1; s < 4; s++) {
        const size_t wso = (size_t)s * 64 * KG;  // weight row offset for this slice
        #pragma unroll
        for (int j = 0; j < 4; j++)
          acc[j] = (floatx4){biasv[s][j], biasv[s][j], biasv[s][j], biasv[s][j]};
        #pragma unroll
        for (int c = 0; c < 9; c++) {  // 36 kts = full K (z segs 0..3 + h segs 4..35)
          #pragma unroll
          for (int i = 0; i < 4; i++) {
            const int k0 = (c * 4 + i) * 32 + quad * 8;
            short8 a = *(const short8*)&lds[row16 * LDP + k0];
            #pragma unroll
            for (int j = 0; j < 4; j++)
              acc[j] = MFMA(a, *(const short8*)(wb[j] + wso + k0), acc[j]);
          }
          SB0();
        }
        #pragma unroll
        for (int r = 0; r < 4; r++) {
          float cn = sigf(acc[1][r]) * creg[s][r] + sigf(acc[0][r]) * tanhfast(acc[2][r]);
          creg[s][r] = cn;
          float hn = sigf(acc[3][r]) * tanhfast(cn);
          __hip_bfloat16 hbf = __float2bfloat16(hn);
          unsigned hu = (unsigned)reinterpret_cast<unsigned short&>(hbf);
          unsigned up = hu | (__shfl_xor(hu, 1, 64) << 16);
          unsigned uq = __shfl_xor(up, 2, 64);
          if ((row16 & 3) == 0) {
            int grow = rowbase + quad * 4 + r;
            int hc = nsb * 256 + s * 64 + w * 16 + row16;
            astore8(AbW + (size_t)grow * KG + Sdim + hc, (ull)up | ((ull)uq << 32));
          }
        }
      }
      __syncthreads();  // drain all waves' h-stores (vmcnt 0) before publishing
      if (tid == 0)
        __hip_atomic_store(&flags[bid], (unsigned)(t + 1),
                           __ATOMIC_RELAXED, __HIP_MEMORY_SCOPE_AGENT);
    } else {
      // --- noise prefetch for all 4 slices (static input), before any wait
      float nz[4][4];
      if (w == 0) {
        #pragma unroll
        for (int ss = 0; ss < 4; ss++)
          #pragma unroll
          for (int r = 0; r < 4; r++) {
            int b = hd_mb * 16 + quad * 4 + r;
            int s = (hd_sbb + ss) * 16 + row16;
            nz[ss][r] = noise[((size_t)b * Tdim + t) * Sdim + s];
          }
      }
      const __hip_bfloat16* axp = xbf + ((size_t)(hd_mb * 16 + row16) * Tdim + t) * DIN;
      const __hip_bfloat16* ahp = AbW + (size_t)(hd_mb * 16 + row16) * KG + Sdim;
      // --- x-part of areg (plain loads; xbf static)
      short8 areg[12];
      #pragma unroll
      for (int kt = 0; kt < 12; kt++)
        if (kt < hd_nx)
          areg[kt] = *(const short8*)(axp + hd_kbase + kt * 32 + quad * 8);

      #pragma unroll
      for (int ss = 0; ss < 4; ss++) {
        const size_t wso = (size_t)ss * 16 * KP;
        floatx4 am, av;
        if (w == 0) { am = (floatx4){hbm4[ss], hbm4[ss], hbm4[ss], hbm4[ss]};
                      av = (floatx4){hbv4[ss], hbv4[ss], hbv4[ss], hbv4[ss]}; }
        else        { am = (floatx4){0.f, 0.f, 0.f, 0.f}; av = (floatx4){0.f, 0.f, 0.f, 0.f}; }
        // x-MFMA (slice 0 does this BEFORE the h-wait -> overlap)
        #pragma unroll
        for (int kt = 0; kt < 12; kt++) {
          if (kt < hd_nx) {
            int k0 = hd_kbase + kt * 32 + quad * 8;
            am = MFMA(areg[kt], *(const short8*)(hd_bpm + wso + k0), am);
            av = MFMA(areg[kt], *(const short8*)(hd_bpv + wso + k0), av);
          }
        }
        if (ss == 0) {
          // --- h-wait: the 4 gates blocks covering my rows finished step t
          if (w == 0) waitflags(flags, hd_mb * 4, 3, (unsigned)(t + 1), lane);
          __syncthreads();
          #pragma unroll
          for (int kt = 0; kt < 12; kt++)
            if (kt >= hd_nx)
              areg[kt] = cload16(ahp + hd_kbase + kt * 32 + quad * 8 - DIN);
          VMWAIT0();
        }
        // h-MFMA
        #pragma unroll
        for (int kt = 0; kt < 12; kt++) {
          if (kt >= hd_nx) {
            int k0 = hd_kbase + kt * 32 + quad * 8;
            am = MFMA(areg[kt], *(const short8*)(hd_bpm + wso + k0), am);
            av = MFMA(areg[kt], *(const short8*)(hd_bpv + wso + k0), av);
          }
        }
        SB0();
        // --- cross-wave K reduction through LDS
        #pragma unroll
        for (int r = 0; r < 4; r++) {
          smem[(w * 2 + 0) * 256 + lane * 4 + r] = am[r];
          smem[(w * 2 + 1) * 256 + lane * 4 + r] = av[r];
        }
        __syncthreads();
        if (w == 0) {
          #pragma unroll
          for (int r = 0; r < 4; r++) {
            int idx = lane * 4 + r;
            float mean = smem[0 * 256 + idx] + smem[2 * 256 + idx] +
                         smem[4 * 256 + idx] + smem[6 * 256 + idx];
            float lv = smem[1 * 256 + idx] + smem[3 * 256 + idx] +
                       smem[5 * 256 + idx] + smem[7 * 256 + idx];
            int b = hd_mb * 16 + quad * 4 + r;
            int s = (hd_sbb + ss) * 16 + row16;
            float std = __expf(0.5f * lv);
            float z = nz[ss][r] * std + mean;
            __hip_bfloat16 zb = __float2bfloat16(z);
            zall[((size_t)b * Tdim + t) * Sdim + s] = zb;  // scan-private store
            unsigned zu = (unsigned)reinterpret_cast<unsigned short&>(zb);
            unsigned up = zu | (__shfl_xor(zu, 1, 64) << 16);
            unsigned uq = __shfl_xor(up, 2, 64);
            if ((row16 & 3) == 0)
              astore8(AbW + (size_t)b * KG + s, (ull)up | ((ull)uq << 32));
            klw += std * std + mean * mean - 0.5f * lv - 0.5f;  // log(std)=0.5*lv
          }
        }
        __syncthreads();  // smem reuse + w0 store drain
      }
      if (tid == 0)
        __hip_atomic_store(&flags[GBLK + (bid - GBLK)], (unsigned)(t + 1),
                           __ATOMIC_RELAXED, __HIP_MEMORY_SCOPE_AGENT);
    }
  }
  // heads w0: one atomic per block for the whole scan
  if (!is_gates && w == 0) {
    #pragma unroll
    for (int off = 32; off > 0; off >>= 1) klw += __shfl_down(klw, off, 64);
    if (lane == 0) atomicAdd(klacc, klw);
  }
}

// ---------------- decoder GEMM1: Hbuf = relu(zall[32768,128] @ Wd1^T + bd1) -> bf16
__global__ __launch_bounds__(256) void dec1_kernel(char* __restrict__ ws,
                                                   const float* __restrict__ bd1) {
  const __hip_bfloat16* zall = (const __hip_bfloat16*)(ws + ZALL_OFF);
  const __hip_bfloat16* Wd1b = (const __hip_bfloat16*)(ws + WD1_OFF);
  __hip_bfloat16* Hbuf = (__hip_bfloat16*)(ws + HB_OFF);
  int tid = threadIdx.x, lane = tid & 63, w = tid >> 6;
  int mb = blockIdx.x, nb = blockIdx.y;
  int row16 = lane & 15, quad = lane >> 4;
  int arow = mb * 64 + w * 16 + row16;
  const __hip_bfloat16* aptr = zall + (size_t)arow * Sdim;
  floatx4 acc[4] = {{0.f,0.f,0.f,0.f},{0.f,0.f,0.f,0.f},{0.f,0.f,0.f,0.f},{0.f,0.f,0.f,0.f}};
  #pragma unroll
  for (int kt = 0; kt < Sdim / 32; kt++) {
    int k0 = kt * 32 + quad * 8;
    short8 a = *(const short8*)(aptr + k0);
    #pragma unroll
    for (int j = 0; j < 4; j++) {
      const __hip_bfloat16* bp = Wd1b + (size_t)(nb * 64 + j * 16 + row16) * Sdim;
      acc[j] = MFMA(a, *(const short8*)(bp + k0), acc[j]);
    }
  }
  #pragma unroll
  for (int j = 0; j < 4; j++) {
    int n = nb * 64 + j * 16 + row16;
    float bias = bd1[n];
    #pragma unroll
    for (int r = 0; r < 4; r++) {
      int rr = mb * 64 + w * 16 + quad * 4 + r;
      float v = fmaxf(acc[j][r] + bias, 0.0f);
      Hbuf[(size_t)rr * DHdim + n] = __float2bfloat16(v);
    }
  }
}

// ---------------- decoder GEMM2: out = Hbuf[32768,1024] @ Wd2^T + bd2 -> f32
__global__ __launch_bounds__(256) void dec2_kernel(char* __restrict__ ws,
                                                   const float* __restrict__ bd2,
                                                   float* __restrict__ out) {
  const __hip_bfloat16* Hbuf = (const __hip_bfloat16*)(ws + HB_OFF);
  const __hip_bfloat16* Wd2b = (const __hip_bfloat16*)(ws + WD2_OFF);
  int tid = threadIdx.x, lane = tid & 63, w = tid >> 6;
  int mb = blockIdx.x, nb = blockIdx.y;
  int row16 = lane & 15, quad = lane >> 4;
  int arow = mb * 64 + w * 16 + row16;
  const __hip_bfloat16* aptr = Hbuf + (size_t)arow * DHdim;
  const __hip_bfloat16* bp[4];
  #pragma unroll
  for (int j = 0; j < 4; j++) bp[j] = Wd2b + (size_t)(nb * 64 + j * 16 + row16) * DHdim;
  floatx4 acc[4] = {{0.f,0.f,0.f,0.f},{0.f,0.f,0.f,0.f},{0.f,0.f,0.f,0.f},{0.f,0.f,0.f,0.f}};
  for (int kt = 0; kt < DHdim / 32; kt++) {
    int k0 = kt * 32 + quad * 8;
    short8 a = *(const short8*)(aptr + k0);
    #pragma unroll
    for (int j = 0; j < 4; j++)
      acc[j] = MFMA(a, *(const short8*)(bp[j] + k0), acc[j]);
  }
  #pragma unroll
  for (int j = 0; j < 4; j++) {
    int n = nb * 64 + j * 16 + row16;
    float bias = bd2[n];
    #pragma unroll
    for (int r = 0; r < 4; r++) {
      int rr = mb * 64 + w * 16 + quad * 4 + r;
      out[(size_t)rr * DIN + n] = acc[j][r] + bias;
    }
  }
}

__global__ void kl_write_kernel(const char* __restrict__ ws, float* __restrict__ out) {
  if (threadIdx.x == 0 && blockIdx.x == 0)
    out[16777216] = *(const float*)(ws + KL_OFF);
}

extern "C" void kernel_launch(void* const* d_in, const int* in_sizes, int n_in,
                              void* d_out, int out_size, void* d_ws, size_t ws_size,
                              hipStream_t stream) {
  const float* x = (const float*)d_in[0];
  const float* noise = (const float*)d_in[1];
  const float* W_ih = (const float*)d_in[2];
  const float* W_hh = (const float*)d_in[3];
  const float* b_ih = (const float*)d_in[4];
  const float* b_hh = (const float*)d_in[5];
  const float* Wm = (const float*)d_in[6];
  const float* bm = (const float*)d_in[7];
  const float* Wv = (const float*)d_in[8];
  const float* bv = (const float*)d_in[9];
  const float* Wd1 = (const float*)d_in[10];
  const float* bd1 = (const float*)d_in[11];
  const float* Wd2 = (const float*)d_in[12];
  const float* bd2 = (const float*)d_in[13];
  char* ws = (char*)d_ws;
  float* out = (float*)d_out;

  long long total_prep = 22692033LL;
  int pblocks = (int)((total_prep + 255) / 256);
  prep_kernel<<<pblocks, 256, 0, stream>>>(x, W_ih, W_hh, Wm, Wv, Wd1, Wd2, ws);
  scan_kernel<<<NBLK, 256, 0, stream>>>(ws, noise, b_ih, b_hh, bm, bv);
  dec1_kernel<<<dim3(512, 16), 256, 0, stream>>>(ws, bd1);
  dec2_kernel<<<dim3(512, 8), 256, 0, stream>>>(ws, bd2, out);
  kl_write_kernel<<<1, 64, 0, stream>>>(ws, out);
}

// Round 11
// 5630.491 us; speedup vs baseline: 11.0455x; 11.0455x over previous
//
#include <hip/hip_runtime.h>
#include <hip/hip_bf16.h>

#define Bdim 128
#define Tdim 256
#define DIN 512
#define Hdim 1024
#define Sdim 128
#define DHdim 1024
#define KG 1152   // S + H (gates GEMM K)
#define KP 1536   // DIN + H (heads GEMM K)
#define GBLK 128  // gates blocks: 8 mgrp x 16 ns (16 rows x 256 gate-cols, 8 waves)
#define HBLK 32   // heads blocks: 8 mb x 4 pg (16 rows x 32 s-cols, 8 waves)
#define NBLK 160
#define LDP 1160  // gates LDS A-panel row stride (1152 + 8 pad)
#define HP  1032  // heads LDS h-panel row stride (1024 + 8 pad)

using short8  = __attribute__((ext_vector_type(8))) short;   // 8 bf16 (4 VGPRs)
using floatx4 = __attribute__((ext_vector_type(4))) float;   // MFMA accum
typedef unsigned long long ull;

#define MFMA(a, b, c) __builtin_amdgcn_mfma_f32_16x16x32_bf16((a), (b), (c), 0, 0, 0)

// ---- workspace layout (bytes). Scan-phase staging (xbf/Wg/Wmv) unions with
// Hbuf (decoder intermediate), which is written only after the scan finishes.
#define XBF_OFF   0ull            // 128*256*512 bf16 = 33,554,432
#define WG_OFF    33554432ull     // 4096*1152 bf16 = 9,437,184
#define WMV_OFF   42991616ull     // 256*1536 bf16 = 786,432
#define HB_OFF    0ull            // 32768*1024 bf16 = 67,108,864 (unions scan staging)
#define WD1_OFF   67108864ull     // 1024*128 bf16 = 262,144
#define WD2_OFF   67371008ull     // 512*1024 bf16 = 1,048,576
#define AB_OFF    68419584ull     // 2 x 128*1152 bf16 (ping-pong [z|h]) = 589,824
#define AB_SZ     294912ull
#define ZALL_OFF  69009408ull     // 32768*128 bf16 = 8,388,608
#define KL_OFF    77398016ull     // 1 f32
#define FLG_OFF   77398144ull     // u32 monotonic per-producer seqno flags

__device__ __forceinline__ float sigf(float v) { return 1.0f / (1.0f + __expf(-v)); }
__device__ __forceinline__ float tanhfast(float v) { return 1.0f - 2.0f / (__expf(2.0f * v) + 1.0f); }

// 16B agent-coherent load: ONE coherent transaction.
// Protocol (vmcnt-accounting safety, round-1 lesson): asm loads only outstanding
// inside a staging burst, drained by VMWAIT0 before ANY compiler memory op.
// (vmcnt is per-wave, so other waves' compiler loads are unaffected.)
__device__ __forceinline__ short8 cload16(const __hip_bfloat16* p) {
  short8 r;
  asm volatile("global_load_dwordx4 %0, %1, off sc0 sc1" : "=&v"(r) : "v"(p));
  return r;
}
#define VMWAIT0()                                              \
  do {                                                         \
    asm volatile("s_waitcnt vmcnt(0)" ::: "memory");           \
    __builtin_amdgcn_sched_barrier(0);                         \
  } while (0)
#define SB0() __builtin_amdgcn_sched_barrier(0)

__device__ __forceinline__ void astore8(__hip_bfloat16* p, ull v) {
  __hip_atomic_store((ull*)(void*)p, v, __ATOMIC_RELAXED, __HIP_MEMORY_SCOPE_AGENT);
}

// Wave0-only polling + s_sleep(4) backoff; callers release others via barrier.
__device__ __forceinline__ void waitflags(unsigned* flags, int base, int mask,
                                          unsigned target, int lane) {
  unsigned* p = flags + base + (lane & mask);
  while (!__all((int)(__hip_atomic_load(p, __ATOMIC_RELAXED, __HIP_MEMORY_SCOPE_AGENT) >= target))) {
    __builtin_amdgcn_s_sleep(4);
  }
}

// ---------------- prep: fp32->bf16 conversions, weight packing, state zeroing
__global__ __launch_bounds__(256) void prep_kernel(
    const float* __restrict__ x, const float* __restrict__ W_ih,
    const float* __restrict__ W_hh, const float* __restrict__ Wm,
    const float* __restrict__ Wv, const float* __restrict__ Wd1,
    const float* __restrict__ Wd2, char* __restrict__ ws) {
  long long i = (long long)blockIdx.x * 256 + threadIdx.x;
  if (i < 16777216LL) {  // x -> xbf  [B][T][DIN]
    ((__hip_bfloat16*)(ws + XBF_OFF))[i] = __float2bfloat16(x[i]);
    return;
  }
  i -= 16777216LL;
  if (i < 4718592LL) {  // Wg[4096][1152] = [W_ih | W_hh]
    int j = (int)(i / KG), k = (int)(i % KG);
    float v = (k < Sdim) ? W_ih[j * Sdim + k] : W_hh[(long long)j * Hdim + (k - Sdim)];
    ((__hip_bfloat16*)(ws + WG_OFF))[i] = __float2bfloat16(v);
    return;
  }
  i -= 4718592LL;
  if (i < 393216LL) {  // Wmv[256][1536] = [Wm ; Wv]
    int r = (int)(i / KP), k = (int)(i % KP);
    float v = (r < Sdim) ? Wm[r * KP + k] : Wv[(r - Sdim) * KP + k];
    ((__hip_bfloat16*)(ws + WMV_OFF))[i] = __float2bfloat16(v);
    return;
  }
  i -= 393216LL;
  if (i < 131072LL) { ((__hip_bfloat16*)(ws + WD1_OFF))[i] = __float2bfloat16(Wd1[i]); return; }
  i -= 131072LL;
  if (i < 524288LL) { ((__hip_bfloat16*)(ws + WD2_OFF))[i] = __float2bfloat16(Wd2[i]); return; }
  i -= 524288LL;
  if (i < 147456LL) { ((__hip_bfloat16*)(ws + AB_OFF))[i] = __float2bfloat16(0.0f); return; }  // [z0|h0]=0
  i -= 147456LL;
  if (i == 0) { *((float*)(ws + KL_OFF)) = 0.0f; return; }
  i -= 1;
  if (i < 192LL) { ((unsigned*)(ws + FLG_OFF))[i] = 0u; return; }
}

// ---------------- persistent scan: whole T=256 recurrence in ONE kernel.
// Round-11: 512-thread blocks (idle-wave capacity -> parallelism, not registers).
//  Gates b<128 (mgrp=b>>4, ns=b&15): 16-row LDS A-panel; 8 waves = 4 col-slices
//   x 2 K-halves (per-wave r9 shape: acc[4], 4 weight streams, 16 kts).
//   K-halves combined via padded LDS reduce; z read direct to registers.
//  Heads 128+hb, hb<32 (mb=hb>>2, pg=hb&3): 16-row h-panel in LDS (staged once,
//   1 MB/step total); 8 waves = 2 s-tile groups x 4 K-parts (r9 heads shape).
// Flags: [0..127] gates, [128..159] heads.
__global__ __launch_bounds__(512, 1) void scan_kernel(
    char* __restrict__ ws, const float* __restrict__ noise,
    const float* __restrict__ b_ih, const float* __restrict__ b_hh,
    const float* __restrict__ bm, const float* __restrict__ bv) {
  const __hip_bfloat16* WG = (const __hip_bfloat16*)(ws + WG_OFF);
  const __hip_bfloat16* WMV = (const __hip_bfloat16*)(ws + WMV_OFF);
  const __hip_bfloat16* xbf = (const __hip_bfloat16*)(ws + XBF_OFF);
  __hip_bfloat16* zall = (__hip_bfloat16*)(ws + ZALL_OFF);
  float* klacc = (float*)(ws + KL_OFF);
  unsigned* flags = (unsigned*)(ws + FLG_OFF);

  // gates: panel 16*LDP*2 = 37120 B + reduce 4*1280*4 = 20480 B  -> 57600
  // heads: h-panel 16*HP*2 = 33024 B + reduce 2*8*256*4 = 16384 B -> 49408
  __shared__ __align__(16) char ldsraw[57600];
  __hip_bfloat16* lds = (__hip_bfloat16*)ldsraw;

  const int tid = threadIdx.x;
  const int lane = tid & 63;
  const int w = tid >> 6;           // 0..7
  const int row16 = lane & 15;
  const int quad = lane >> 4;
  const int bid = blockIdx.x;
  const bool is_gates = (bid < GBLK);

  // ---- gates-role setup
  const __hip_bfloat16* gb_bp[4];
  float biasv[4];
  int mgrp = 0, ns = 0, rowbase = 0, cs = 0, khalf = 0;
  float creg[4] = {0.f, 0.f, 0.f, 0.f};
  // ---- heads-role setup
  const __hip_bfloat16* hd_bpm = nullptr;
  const __hip_bfloat16* hd_bpv = nullptr;
  int hd_mb = 0, hd_pg = 0, hd_nx = 0, hd_kbase = 0, hd_g = 0, hd_stile = 0;
  float hbm = 0.f, hbv = 0.f;
  float klw = 0.f;

  if (is_gates) {
    mgrp = bid >> 4;
    ns = bid & 15;
    rowbase = mgrp * 16;
    cs = w & 3;        // col-slice within the block's 256 gate-cols
    khalf = w >> 2;    // 0: h-K 0..15 kts (+z), 1: h-K 16..31 kts
    #pragma unroll
    for (int j = 0; j < 4; j++) {
      int idx = j * Hdim + ns * 64 + cs * 16 + row16;
      gb_bp[j] = WG + (size_t)idx * KG;
      biasv[j] = b_ih[idx] + b_hh[idx];
    }
  } else {
    int hb = bid - GBLK;
    hd_mb = hb >> 2;
    hd_pg = hb & 3;
    hd_g = w >> 2;                  // s-tile group 0/1
    hd_stile = hd_pg * 2 + hd_g;    // 0..7
    int s = hd_stile * 16 + row16;
    hd_bpm = WMV + (size_t)s * KP;
    hd_bpv = WMV + (size_t)(128 + s) * KP;
    hbm = bm[s];
    hbv = bv[s];
    int kp = w & 3;
    hd_kbase = kp * 384;
    hd_nx = (hd_kbase < DIN) ? ((DIN - hd_kbase) >> 5) : 0;  // 12,4,0,0
    if (hd_nx > 12) hd_nx = 12;
  }

  for (int t = 0; t < Tdim; t++) {
    const int par = t & 1;
    const __hip_bfloat16* Ab = (const __hip_bfloat16*)(ws + AB_OFF + (ull)par * AB_SZ);
    __hip_bfloat16* AbW = (__hip_bfloat16*)(ws + AB_OFF + (ull)(par ^ 1) * AB_SZ);

    if (is_gates) {
      float* rsm = (float*)(ldsraw + 37120);  // K-half reduce, stride-20 padded
      floatx4 acc[4];
      #pragma unroll
      for (int j = 0; j < 4; j++)
        acc[j] = (khalf == 0)
          ? (floatx4){biasv[j], biasv[j], biasv[j], biasv[j]}
          : (floatx4){0.f, 0.f, 0.f, 0.f};

      // --- h-wait (own 16-block cohort: WAR + h(t-1) ready)
      if (w == 0) waitflags(flags, mgrp * 16, 15, (unsigned)t, lane);
      __syncthreads();
      // --- stage h-panel into LDS: 2048 16B-segs over 512 threads (4 each)
      {
        short8 sreg[4];
        #pragma unroll
        for (int i = 0; i < 4; i++) {
          int s = tid + i * 512;
          sreg[i] = cload16(Ab + (size_t)(rowbase + (s >> 7)) * KG + Sdim + (s & 127) * 8);
        }
        VMWAIT0();
        #pragma unroll
        for (int i = 0; i < 4; i++) {
          int s = tid + i * 512;
          *(short8*)&lds[(s >> 7) * LDP + Sdim + (s & 127) * 8] = sreg[i];
        }
      }
      __syncthreads();  // panel visible to all waves
      // --- h-region MFMA from LDS: my K-half (16 kts), 4 weight streams
      #pragma unroll
      for (int c = 0; c < 4; c++) {
        #pragma unroll
        for (int i = 0; i < 4; i++) {
          const int k0 = Sdim + (khalf * 16 + c * 4 + i) * 32 + quad * 8;
          short8 a = *(const short8*)&lds[row16 * LDP + k0];
          #pragma unroll
          for (int j = 0; j < 4; j++)
            acc[j] = MFMA(a, *(const short8*)(gb_bp[j] + k0), acc[j]);
        }
        SB0();
      }
      // khalf1: publish partials to reduce smem (padded stride: 2-way max)
      if (khalf == 1) {
        #pragma unroll
        for (int j = 0; j < 4; j++)
          *(floatx4*)&rsm[cs * 1280 + lane * 20 + j * 4] = acc[j];
      }
      // --- z-wait (heads blocks for my rows, step t-1)
      if (w == 0) waitflags(flags, GBLK + mgrp * 4, 3, (unsigned)t, lane);
      __syncthreads();  // partials visible; z published
      if (khalf == 0) {
        // z direct to registers (each lane reads its data-row's z fragment)
        const __hip_bfloat16* zp = Ab + (size_t)(rowbase + row16) * KG;
        short8 zreg[4];
        #pragma unroll
        for (int kt = 0; kt < 4; kt++)
          zreg[kt] = cload16(zp + kt * 32 + quad * 8);
        VMWAIT0();
        #pragma unroll
        for (int kt = 0; kt < 4; kt++) {
          const int k0 = kt * 32 + quad * 8;
          #pragma unroll
          for (int j = 0; j < 4; j++)
            acc[j] = MFMA(zreg[kt], *(const short8*)(gb_bp[j] + k0), acc[j]);
        }
        SB0();
        // combine K-halves + LSTM + packed 8B h-store
        #pragma unroll
        for (int j = 0; j < 4; j++)
          acc[j] += *(const floatx4*)&rsm[cs * 1280 + lane * 20 + j * 4];
        #pragma unroll
        for (int r = 0; r < 4; r++) {
          float cn = sigf(acc[1][r]) * creg[r] + sigf(acc[0][r]) * tanhfast(acc[2][r]);
          creg[r] = cn;
          float hn = sigf(acc[3][r]) * tanhfast(cn);
          __hip_bfloat16 hbf = __float2bfloat16(hn);
          unsigned hu = (unsigned)reinterpret_cast<unsigned short&>(hbf);
          unsigned up = hu | (__shfl_xor(hu, 1, 64) << 16);
          unsigned uq = __shfl_xor(up, 2, 64);
          if ((row16 & 3) == 0) {
            int grow = rowbase + quad * 4 + r;
            int hc = ns * 64 + cs * 16 + row16;
            astore8(AbW + (size_t)grow * KG + Sdim + hc, (ull)up | ((ull)uq << 32));
          }
        }
      }
      __syncthreads();  // drain khalf0 h-stores before publishing
      if (tid == 0)
        __hip_atomic_store(&flags[bid], (unsigned)(t + 1),
                           __ATOMIC_RELAXED, __HIP_MEMORY_SCOPE_AGENT);
    } else {
      float* smf = (float*)(ldsraw + 33024);  // cross-K reduce: [g][kp*2+c][256]
      // --- noise prefetch (finalizer waves), before any wait
      float nz[4];
      if ((w & 3) == 0) {
        #pragma unroll
        for (int r = 0; r < 4; r++) {
          int b = hd_mb * 16 + quad * 4 + r;
          int s = hd_stile * 16 + row16;
          nz[r] = noise[((size_t)b * Tdim + t) * Sdim + s];
        }
      }
      // --- x-region (static input, plain loads; no wait)
      const __hip_bfloat16* axp = xbf + ((size_t)(hd_mb * 16 + row16) * Tdim + t) * DIN;
      floatx4 am = {0.f, 0.f, 0.f, 0.f}, av = {0.f, 0.f, 0.f, 0.f};
      {
        short8 areg[12];
        #pragma unroll
        for (int kt = 0; kt < 12; kt++)
          if (kt < hd_nx)
            areg[kt] = *(const short8*)(axp + hd_kbase + kt * 32 + quad * 8);
        #pragma unroll
        for (int kt = 0; kt < 12; kt++) {
          if (kt < hd_nx) {
            int k0 = hd_kbase + kt * 32 + quad * 8;
            am = MFMA(areg[kt], *(const short8*)(hd_bpm + k0), am);
            av = MFMA(areg[kt], *(const short8*)(hd_bpv + k0), av);
          }
        }
      }
      // --- h-wait: the 16 gates blocks covering my rows finished step t
      if (w == 0) waitflags(flags, hd_mb * 16, 15, (unsigned)(t + 1), lane);
      __syncthreads();
      // --- stage h-panel (16 x 1024) into LDS: 2048 segs over 512 thr
      {
        short8 sreg[4];
        #pragma unroll
        for (int i = 0; i < 4; i++) {
          int s = tid + i * 512;
          sreg[i] = cload16(AbW + (size_t)(hd_mb * 16 + (s >> 7)) * KG + Sdim + (s & 127) * 8);
        }
        VMWAIT0();
        #pragma unroll
        for (int i = 0; i < 4; i++) {
          int s = tid + i * 512;
          *(short8*)&lds[(s >> 7) * HP + (s & 127) * 8] = sreg[i];
        }
      }
      __syncthreads();
      // --- h-region MFMA from LDS (my K-part)
      #pragma unroll
      for (int kt = 0; kt < 12; kt++) {
        if (kt >= hd_nx) {
          int k0 = hd_kbase + kt * 32 + quad * 8;
          short8 a = *(const short8*)&lds[row16 * HP + (k0 - DIN)];
          am = MFMA(a, *(const short8*)(hd_bpm + k0), am);
          av = MFMA(a, *(const short8*)(hd_bpv + k0), av);
        }
      }
      SB0();
      // --- cross-K reduction through LDS (per s-tile group)
      {
        int kp = w & 3;
        #pragma unroll
        for (int r = 0; r < 4; r++) {
          smf[hd_g * 2048 + (kp * 2 + 0) * 256 + lane * 4 + r] = am[r];
          smf[hd_g * 2048 + (kp * 2 + 1) * 256 + lane * 4 + r] = av[r];
        }
      }
      __syncthreads();
      if ((w & 3) == 0) {
        #pragma unroll
        for (int r = 0; r < 4; r++) {
          int idx = lane * 4 + r;
          float mean = hbm + smf[hd_g * 2048 + 0 * 256 + idx] + smf[hd_g * 2048 + 2 * 256 + idx] +
                       smf[hd_g * 2048 + 4 * 256 + idx] + smf[hd_g * 2048 + 6 * 256 + idx];
          float lv = hbv + smf[hd_g * 2048 + 1 * 256 + idx] + smf[hd_g * 2048 + 3 * 256 + idx] +
                     smf[hd_g * 2048 + 5 * 256 + idx] + smf[hd_g * 2048 + 7 * 256 + idx];
          int b = hd_mb * 16 + quad * 4 + r;
          int s = hd_stile * 16 + row16;
          float std = __expf(0.5f * lv);
          float z = nz[r] * std + mean;
          __hip_bfloat16 zb = __float2bfloat16(z);
          zall[((size_t)b * Tdim + t) * Sdim + s] = zb;  // scan-private store
          unsigned zu = (unsigned)reinterpret_cast<unsigned short&>(zb);
          unsigned up = zu | (__shfl_xor(zu, 1, 64) << 16);
          unsigned uq = __shfl_xor(up, 2, 64);
          if ((row16 & 3) == 0)
            astore8(AbW + (size_t)b * KG + s, (ull)up | ((ull)uq << 32));
          klw += std * std + mean * mean - 0.5f * lv - 0.5f;  // log(std)=0.5*lv
        }
      }
      __syncthreads();  // finalizer stores drained + smem reusable
      if (tid == 0)
        __hip_atomic_store(&flags[bid], (unsigned)(t + 1),
                           __ATOMIC_RELAXED, __HIP_MEMORY_SCOPE_AGENT);
    }
  }
  // heads finalizer waves: one atomic each for the whole scan
  if (!is_gates && (w & 3) == 0) {
    #pragma unroll
    for (int off = 32; off > 0; off >>= 1) klw += __shfl_down(klw, off, 64);
    if (lane == 0) atomicAdd(klacc, klw);
  }
}

// ---------------- decoder GEMM1: Hbuf = relu(zall[32768,128] @ Wd1^T + bd1) -> bf16
__global__ __launch_bounds__(256) void dec1_kernel(char* __restrict__ ws,
                                                   const float* __restrict__ bd1) {
  const __hip_bfloat16* zall = (const __hip_bfloat16*)(ws + ZALL_OFF);
  const __hip_bfloat16* Wd1b = (const __hip_bfloat16*)(ws + WD1_OFF);
  __hip_bfloat16* Hbuf = (__hip_bfloat16*)(ws + HB_OFF);
  int tid = threadIdx.x, lane = tid & 63, w = tid >> 6;
  int mb = blockIdx.x, nb = blockIdx.y;
  int row16 = lane & 15, quad = lane >> 4;
  int arow = mb * 64 + w * 16 + row16;
  const __hip_bfloat16* aptr = zall + (size_t)arow * Sdim;
  floatx4 acc[4] = {{0.f,0.f,0.f,0.f},{0.f,0.f,0.f,0.f},{0.f,0.f,0.f,0.f},{0.f,0.f,0.f,0.f}};
  #pragma unroll
  for (int kt = 0; kt < Sdim / 32; kt++) {
    int k0 = kt * 32 + quad * 8;
    short8 a = *(const short8*)(aptr + k0);
    #pragma unroll
    for (int j = 0; j < 4; j++) {
      const __hip_bfloat16* bp = Wd1b + (size_t)(nb * 64 + j * 16 + row16) * Sdim;
      acc[j] = MFMA(a, *(const short8*)(bp + k0), acc[j]);
    }
  }
  #pragma unroll
  for (int j = 0; j < 4; j++) {
    int n = nb * 64 + j * 16 + row16;
    float bias = bd1[n];
    #pragma unroll
    for (int r = 0; r < 4; r++) {
      int rr = mb * 64 + w * 16 + quad * 4 + r;
      float v = fmaxf(acc[j][r] + bias, 0.0f);
      Hbuf[(size_t)rr * DHdim + n] = __float2bfloat16(v);
    }
  }
}

// ---------------- decoder GEMM2: out = Hbuf[32768,1024] @ Wd2^T + bd2 -> f32
__global__ __launch_bounds__(256) void dec2_kernel(char* __restrict__ ws,
                                                   const float* __restrict__ bd2,
                                                   float* __restrict__ out) {
  const __hip_bfloat16* Hbuf = (const __hip_bfloat16*)(ws + HB_OFF);
  const __hip_bfloat16* Wd2b = (const __hip_bfloat16*)(ws + WD2_OFF);
  int tid = threadIdx.x, lane = tid & 63, w = tid >> 6;
  int mb = blockIdx.x, nb = blockIdx.y;
  int row16 = lane & 15, quad = lane >> 4;
  int arow = mb * 64 + w * 16 + row16;
  const __hip_bfloat16* aptr = Hbuf + (size_t)arow * DHdim;
  const __hip_bfloat16* bp[4];
  #pragma unroll
  for (int j = 0; j < 4; j++) bp[j] = Wd2b + (size_t)(nb * 64 + j * 16 + row16) * DHdim;
  floatx4 acc[4] = {{0.f,0.f,0.f,0.f},{0.f,0.f,0.f,0.f},{0.f,0.f,0.f,0.f},{0.f,0.f,0.f,0.f}};
  for (int kt = 0; kt < DHdim / 32; kt++) {
    int k0 = kt * 32 + quad * 8;
    short8 a = *(const short8*)(aptr + k0);
    #pragma unroll
    for (int j = 0; j < 4; j++)
      acc[j] = MFMA(a, *(const short8*)(bp[j] + k0), acc[j]);
  }
  #pragma unroll
  for (int j = 0; j < 4; j++) {
    int n = nb * 64 + j * 16 + row16;
    float bias = bd2[n];
    #pragma unroll
    for (int r = 0; r < 4; r++) {
      int rr = mb * 64 + w * 16 + quad * 4 + r;
      out[(size_t)rr * DIN + n] = acc[j][r] + bias;
    }
  }
}

__global__ void kl_write_kernel(const char* __restrict__ ws, float* __restrict__ out) {
  if (threadIdx.x == 0 && blockIdx.x == 0)
    out[16777216] = *(const float*)(ws + KL_OFF);
}

extern "C" void kernel_launch(void* const* d_in, const int* in_sizes, int n_in,
                              void* d_out, int out_size, void* d_ws, size_t ws_size,
                              hipStream_t stream) {
  const float* x = (const float*)d_in[0];
  const float* noise = (const float*)d_in[1];
  const float* W_ih = (const float*)d_in[2];
  const float* W_hh = (const float*)d_in[3];
  const float* b_ih = (const float*)d_in[4];
  const float* b_hh = (const float*)d_in[5];
  const float* Wm = (const float*)d_in[6];
  const float* bm = (const float*)d_in[7];
  const float* Wv = (const float*)d_in[8];
  const float* bv = (const float*)d_in[9];
  const float* Wd1 = (const float*)d_in[10];
  const float* bd1 = (const float*)d_in[11];
  const float* Wd2 = (const float*)d_in[12];
  const float* bd2 = (const float*)d_in[13];
  char* ws = (char*)d_ws;
  float* out = (float*)d_out;

  long long total_prep = 22692033LL;
  int pblocks = (int)((total_prep + 255) / 256);
  prep_kernel<<<pblocks, 256, 0, stream>>>(x, W_ih, W_hh, Wm, Wv, Wd1, Wd2, ws);
  scan_kernel<<<NBLK, 512, 0, stream>>>(ws, noise, b_ih, b_hh, bm, bv);
  dec1_kernel<<<dim3(512, 16), 256, 0, stream>>>(ws, bd1);
  dec2_kernel<<<dim3(512, 8), 256, 0, stream>>>(ws, bd2, out);
  kl_write_kernel<<<1, 64, 0, stream>>>(ws, out);
}